// Round 12
// baseline (293.922 us; speedup 1.0000x reference)
//
#include <hip/hip_runtime.h>
#include <stdint.h>

#define B_ 2
#define S_ 1024
#define D_ 4096
#define H_ 32
#define KVH_ 8
#define HD_ 128

typedef short short8 __attribute__((ext_vector_type(8)));
typedef float floatx4 __attribute__((ext_vector_type(4)));

__device__ __forceinline__ ushort f2bf(float f) {
  union { float f; uint32_t u; } v; v.f = f;
  return (ushort)((v.u + 0x7FFFu + ((v.u >> 16) & 1u)) >> 16);
}
__device__ __forceinline__ float bf2f(ushort u) {
  union { uint32_t x; float f; } v; v.x = ((uint32_t)u) << 16; return v.f;
}

__device__ __forceinline__ void gload16(const void* g, void* l) {
  __builtin_amdgcn_global_load_lds((__attribute__((address_space(1))) void*)g,
                                   (__attribute__((address_space(3))) void*)l,
                                   16, 0, 0);
}

// ---- fused: x f32 -> bf16  AND  xa = x @ [lora_q_a | lora_v_a] ----
__global__ __launch_bounds__(256) void k_cvtlora(const float* __restrict__ x,
                                                 const float* __restrict__ qa,
                                                 const float* __restrict__ va,
                                                 ushort* __restrict__ xb,
                                                 float* __restrict__ xa) {
  const int row = blockIdx.x, t = threadIdx.x;
  const float* xr = x + (size_t)row * D_;
  ushort* xo = xb + (size_t)row * D_;
  float a0 = 0, a1 = 0, a2 = 0, a3 = 0;
#pragma unroll
  for (int it = 0; it < 4; it++) {
    const int i = it * 1024 + t * 4;
    float4 v = *(const float4*)(xr + i);
    ushort o4[4] = {f2bf(v.x), f2bf(v.y), f2bf(v.z), f2bf(v.w)};
    *(uint2*)(xo + i) = *(uint2*)o4;
    float4 q0 = *(const float4*)(qa + 2 * i);
    float4 q1 = *(const float4*)(qa + 2 * i + 4);
    float4 w0 = *(const float4*)(va + 2 * i);
    float4 w1 = *(const float4*)(va + 2 * i + 4);
    a0 += v.x * q0.x + v.y * q0.z + v.z * q1.x + v.w * q1.z;
    a1 += v.x * q0.y + v.y * q0.w + v.z * q1.y + v.w * q1.w;
    a2 += v.x * w0.x + v.y * w0.z + v.z * w1.x + v.w * w1.z;
    a3 += v.x * w0.y + v.y * w0.w + v.z * w1.y + v.w * w1.w;
  }
#pragma unroll
  for (int off = 32; off; off >>= 1) {
    a0 += __shfl_down(a0, off, 64);
    a1 += __shfl_down(a1, off, 64);
    a2 += __shfl_down(a2, off, 64);
    a3 += __shfl_down(a3, off, 64);
  }
  __shared__ float red[4][4];
  const int w = t >> 6, lane = t & 63;
  if (lane == 0) { red[w][0] = a0; red[w][1] = a1; red[w][2] = a2; red[w][3] = a3; }
  __syncthreads();
  if (t < 4)
    xa[(size_t)row * 4 + t] = red[0][t] + red[1][t] + red[2][t] + red[3][t];
}

// ---- f32 [R x C] -> bf16 transposed [C x R]; 64x64 tiles; z picks src ----
__global__ __launch_bounds__(256) void k_trw2(const float* __restrict__ in0,
                                              const float* __restrict__ in1,
                                              ushort* __restrict__ out0,
                                              ushort* __restrict__ out1,
                                              int in_stride, int out_stride) {
  const float* in = blockIdx.z ? in1 : in0;
  ushort* out = blockIdx.z ? out1 : out0;
  __shared__ float t[64][65];
  const int n0 = blockIdx.x * 64, k0 = blockIdx.y * 64;
  const int c4 = (threadIdx.x & 15) * 4, r = threadIdx.x >> 4;
#pragma unroll
  for (int rr = 0; rr < 64; rr += 16) {
    float4 v = *(const float4*)&in[(size_t)(k0 + r + rr) * in_stride + n0 + c4];
    t[r + rr][c4] = v.x; t[r + rr][c4 + 1] = v.y;
    t[r + rr][c4 + 2] = v.z; t[r + rr][c4 + 3] = v.w;
  }
  __syncthreads();
#pragma unroll
  for (int rr = 0; rr < 64; rr += 16) {
    const int n = r + rr;
    ushort o4[4] = {f2bf(t[c4][n]), f2bf(t[c4 + 1][n]),
                    f2bf(t[c4 + 2][n]), f2bf(t[c4 + 3][n])};
    *(uint2*)&out[(size_t)(n0 + n) * out_stride + k0 + c4] = *(uint2*)o4;
  }
}

#define GBAR __builtin_amdgcn_s_barrier()
#define VMCNT0 asm volatile("s_waitcnt vmcnt(0)" ::: "memory")
#define VMCNT6 asm volatile("s_waitcnt vmcnt(6)" ::: "memory")

// ==================== QKV GEMM: 128x384 tile, BK=64, 2-buffer =============
#define QSTG(T, SB) do {                                                     \
    const ushort* ga_ = A + (size_t)(m0 + w * 16 + qsr) * Kz + (T) * 64 + qsc; \
    char* la_ = qlds + (SB) * 65536 + w * 2048;                              \
    gload16(ga_, la_); gload16(ga_ + 8 * Kz, la_ + 1024);                    \
    _Pragma("unroll") for (int u_ = 0; u_ < 3; u_++) {                       \
      const ushort* gb_ = Bt + (size_t)(n0 + u_ * 128 + w * 16 + qsr) * Kz   \
                          + (T) * 64 + qsc;                                  \
      char* lb_ = qlds + (SB) * 65536 + 16384 + u_ * 16384 + w * 2048;       \
      gload16(gb_, lb_); gload16(gb_ + 8 * Kz, lb_ + 1024);                  \
    }                                                                        \
  } while (0)

__global__ __launch_bounds__(512, 2) void k_gemmq(const ushort* __restrict__ A,
                                                  const ushort* __restrict__ Bt,
                                                  ushort* __restrict__ Qb,
                                                  ushort* __restrict__ Kb,
                                                  ushort* __restrict__ Vt,
                                                  const float* __restrict__ xa,
                                                  const float* __restrict__ qb,
                                                  const float* __restrict__ vb,
                                                  const float* __restrict__ fcos,
                                                  const float* __restrict__ fsin) {
  __shared__ char qlds[131072];
  const int flat = blockIdx.y * 16 + blockIdx.x;
  const int swz_id = (flat & 7) * 32 + (flat >> 3);
  const int m0 = (swz_id >> 4) * 128, n0 = (swz_id & 15) * 384;
  const int tid = threadIdx.x, lane = tid & 63, w = tid >> 6;
  const int wr = w >> 2, wc = w & 3;
  const int lr = lane & 15, g = lane >> 4;
  const int swz = (lr & 7) * 16;
  const size_t Kz = 4096;
  const int qsr = lane >> 3;                       // 0..7
  const int qsc = ((lane & 7) ^ (qsr & 7)) * 8;    // pre-swizzled source col

  floatx4 acc[4][6] = {};
  short8 af[4][2], bfr[6][2];

  QSTG(0, 0);
  VMCNT0;
  GBAR;

  for (int t = 0; t < 64; ++t) {
    const int bu = t & 1;
    if (t + 1 < 64) QSTG(t + 1, bu ^ 1);
    const char* ab_ = qlds + bu * 65536 + (wr * 64 + lr) * 128;
#pragma unroll
    for (int fr = 0; fr < 4; fr++)
#pragma unroll
      for (int ks = 0; ks < 2; ks++)
        af[fr][ks] = *(const short8*)(ab_ + fr * 2048 + (((ks * 4 + g) * 16) ^ swz));
    const char* bb_ = qlds + bu * 65536 + 16384 + (wc * 32 + lr) * 128;
#pragma unroll
    for (int u = 0; u < 3; u++)
#pragma unroll
      for (int e = 0; e < 2; e++)
#pragma unroll
        for (int ks = 0; ks < 2; ks++)
          bfr[u * 2 + e][ks] = *(const short8*)(bb_ + u * 16384 + e * 2048 +
                                                (((ks * 4 + g) * 16) ^ swz));
    __builtin_amdgcn_s_setprio(1);
#pragma unroll
    for (int fr = 0; fr < 4; fr++)
#pragma unroll
      for (int u = 0; u < 6; u++)
#pragma unroll
        for (int ks = 0; ks < 2; ks++)
          acc[fr][u] = __builtin_amdgcn_mfma_f32_16x16x32_bf16(
              af[fr][ks], bfr[u][ks], acc[fr][u], 0, 0, 0);
    __builtin_amdgcn_s_setprio(0);
    VMCNT0;
    GBAR;
  }

  // epilogue: LoRA + RoPE fused; scatter to Qb/Kb/(transposed)Vt
#pragma unroll
  for (int fr = 0; fr < 4; fr++) {
    const int mb = m0 + wr * 64 + fr * 16 + g * 4;
    const int bb = mb >> 10, s0 = mb & 1023;
    float4 xa4[4];
#pragma unroll
    for (int r = 0; r < 4; r++) xa4[r] = *(const float4*)&xa[(size_t)(mb + r) * 4];
#pragma unroll
    for (int j = 0; j < 3; j++)
#pragma unroll
      for (int e = 0; e < 2; e++) {
        const int n = n0 + j * 128 + wc * 32 + e * 16 + lr;
        if (n < 5120) {
          const bool lq = (n < 4096);
          float b0 = 0.f, b1 = 0.f;
          if (lq) { b0 = qb[n]; b1 = qb[4096 + n]; }
          const int p = (n & 127) >> 1;
          const bool even = !(n & 1);
          const int d = n & 127;
          ushort* dst = lq ? (Qb + ((size_t)(bb * H_ + (n >> 7)) * S_) * HD_ + d)
                           : (Kb + ((size_t)(bb * KVH_ + ((n - 4096) >> 7)) * S_) * HD_ + d);
#pragma unroll
          for (int r = 0; r < 4; r++) {
            float cc = acc[fr][j * 2 + e][r];
            if (lq) cc += xa4[r].x * b0 + xa4[r].y * b1;
            float pv = __shfl_xor(cc, 1, 64);
            const int s = s0 + r;
            float c = fcos[s * 64 + p], sn = fsin[s * 64 + p];
            float o = even ? (cc * c - pv * sn) : (cc * c + pv * sn);
            dst[(size_t)s * HD_] = f2bf(o);
          }
        } else {
          const int vcol = n - 5120;
          const float b0 = vb[vcol], b1 = vb[1024 + vcol];
          ushort v4[4];
#pragma unroll
          for (int r = 0; r < 4; r++)
            v4[r] = f2bf(acc[fr][j * 2 + e][r] + xa4[r].z * b0 + xa4[r].w * b1);
          *(uint2*)&Vt[(size_t)((bb * 8 + (vcol >> 7)) * 128 + (vcol & 127)) * 1024 + s0] =
              *(uint2*)v4;
        }
      }
  }
}

// ==================== out-proj GEMM: 128x256 tile, BK=64, 3-buffer ========
#define OSTG(T, SB) do {                                                     \
    const ushort* ga_ = A + (size_t)(m0 + w * 16 + osr) * Kz + (T) * 64 + osc; \
    char* la_ = olds + (SB) * 49152 + w * 2048;                              \
    gload16(ga_, la_); gload16(ga_ + 8 * Kz, la_ + 1024);                    \
    _Pragma("unroll") for (int u_ = 0; u_ < 2; u_++) {                       \
      const ushort* gb_ = Bt + (size_t)(n0 + u_ * 128 + w * 16 + osr) * Kz + (T) * 64 + osc; \
      char* lb_ = olds + (SB) * 49152 + 16384 + u_ * 16384 + w * 2048;       \
      gload16(gb_, lb_); gload16(gb_ + 8 * Kz, lb_ + 1024);                  \
    }                                                                        \
  } while (0)

#define OTILE(T, RB) do {                                                    \
    if ((T) + 2 < 64) OSTG((T) + 2, ((RB) + 2) % 3);                         \
    const char* ab_ = olds + (RB) * 49152 + (wr * 64 + lr) * 128;            \
    _Pragma("unroll") for (int fr = 0; fr < 4; fr++)                         \
    _Pragma("unroll") for (int ks = 0; ks < 2; ks++)                         \
      af[fr][ks] = *(const short8*)(ab_ + fr * 2048 + (((ks * 4 + g) * 16) ^ swz)); \
    const char* bb_ = olds + (RB) * 49152 + 16384 + (wc * 32 + lr) * 128;    \
    _Pragma("unroll") for (int u_ = 0; u_ < 2; u_++)                         \
    _Pragma("unroll") for (int e_ = 0; e_ < 2; e_++)                         \
    _Pragma("unroll") for (int ks = 0; ks < 2; ks++)                         \
      bfr[u_ * 2 + e_][ks] = *(const short8*)(bb_ + u_ * 16384 + e_ * 2048 + (((ks * 4 + g) * 16) ^ swz)); \
    __builtin_amdgcn_s_setprio(1);                                           \
    _Pragma("unroll") for (int fr = 0; fr < 4; fr++)                         \
    _Pragma("unroll") for (int u_ = 0; u_ < 4; u_++)                         \
    _Pragma("unroll") for (int ks = 0; ks < 2; ks++)                         \
      acc[fr][u_] = __builtin_amdgcn_mfma_f32_16x16x32_bf16(                 \
          af[fr][ks], bfr[u_][ks], acc[fr][u_], 0, 0, 0);                    \
    __builtin_amdgcn_s_setprio(0);                                           \
    if ((T) + 2 < 64) { VMCNT6; } else { VMCNT0; }                           \
    GBAR;                                                                    \
  } while (0)

__global__ __launch_bounds__(512, 2) void k_gemmo(const ushort* __restrict__ A,
                                                  const ushort* __restrict__ Bt,
                                                  float* __restrict__ C) {
  __shared__ char olds[147456];
  const int flat = blockIdx.y * 16 + blockIdx.x;
  const int swz_id = (flat & 7) * 32 + (flat >> 3);
  const int m0 = (swz_id >> 4) * 128, n0 = (swz_id & 15) * 256;
  const int tid = threadIdx.x, lane = tid & 63, w = tid >> 6;
  const int wr = w >> 2, wc = w & 3;
  const int lr = lane & 15, g = lane >> 4;
  const int swz = (lr & 7) * 16;
  const size_t Kz = 4096;
  const int osr = lane >> 3;
  const int osc = ((lane & 7) ^ (osr & 7)) * 8;

  floatx4 acc[4][4] = {};
  short8 af[4][2], bfr[4][2];

  OSTG(0, 0); OSTG(1, 1);
  VMCNT6;
  GBAR;

  for (int tt = 0; tt < 63; tt += 3) {
    OTILE(tt + 0, 0);
    OTILE(tt + 1, 1);
    OTILE(tt + 2, 2);
  }
  OTILE(63, 0);

#pragma unroll
  for (int fr = 0; fr < 4; fr++) {
    const int mb = m0 + wr * 64 + fr * 16 + g * 4;
#pragma unroll
    for (int j = 0; j < 2; j++)
#pragma unroll
      for (int e = 0; e < 2; e++) {
        const int n = n0 + j * 128 + wc * 32 + e * 16 + lr;
#pragma unroll
        for (int r = 0; r < 4; r++)
          C[(size_t)(mb + r) * 4096 + n] = acc[fr][j * 2 + e][r];
      }
  }
}

// ==================== flash attention, 256 q-rows/block ====================
// grid (4, 32, 2), 512 threads (8 waves). Each wave owns q-groups a (+0) and
// b (+128) of 16 rows. KV visits per (h,b): 4q+4 summed = 40 (vs 72 at 128
// rows) -> 0.55x staging/barriers. LDS 96KB: K dbuf 32K | V dbuf 32K | P 32K.
#define FSTAGE(T, DB) do {                                                   \
    gload16(Kg + (size_t)((T) * 64 + krow) * HD_ + kcol,                     \
            fls + (DB) * 16384 + w * 1024);                                  \
    gload16(Kg + (size_t)((T) * 64 + 32 + krow) * HD_ + kcol,                \
            fls + (DB) * 16384 + 8192 + w * 1024);                           \
    gload16(Vg + (size_t)vrow * S_ + (T) * 64 + vcol,                        \
            fls + 32768 + (DB) * 16384 + w * 1024);                          \
    gload16(Vg + (size_t)(64 + vrow) * S_ + (T) * 64 + vcol,                 \
            fls + 32768 + (DB) * 16384 + 8192 + w * 1024);                   \
  } while (0)

__global__ __launch_bounds__(512, 2) void k_flash(const ushort* __restrict__ Qb,
                                                  const ushort* __restrict__ Kb,
                                                  const ushort* __restrict__ Vt,
                                                  ushort* __restrict__ attn) {
  __shared__ char fls[98304];
  const int qblk = 3 - blockIdx.x;  // heavy blocks first
  const int h = blockIdx.y, b = blockIdx.z;
  const int kvh = h >> 2;
  const int tid = threadIdx.x, w = tid >> 6, lane = tid & 63;
  const int lr = lane & 15, g = lane >> 4;
  const int swz = (lr & 7) * 16;
  const int qra = qblk * 256 + w * 16;     // group a rows; group b = +128
  const ushort* Qrow = Qb + ((size_t)(b * H_ + h) * S_ + qra + lr) * HD_;
  short8 qfa[4], qfb[4];
#pragma unroll
  for (int ks = 0; ks < 4; ks++) {
    qfa[ks] = *(const short8*)(Qrow + ks * 32 + g * 8);
    qfb[ks] = *(const short8*)(Qrow + 128 * HD_ + ks * 32 + g * 8);
  }
  const ushort* Kg = Kb + (size_t)(b * KVH_ + kvh) * S_ * HD_;
  const ushort* Vg = Vt + (size_t)(b * KVH_ + kvh) * HD_ * S_;
  char* Pw = fls + 65536 + w * 4096;       // a at +0, b at +2048
  const int q7 = lr & 7;
  const int krow = tid >> 4;                         // 0..31
  const int kcol = ((tid & 15) ^ (krow & 7)) * 8;    // pre-swizzled
  const int vrow = tid >> 3;                         // 0..63
  const int vcol = ((tid & 7) ^ (vrow & 7)) * 8;
  const float scale = 0.088388347648318447f;  // 1/sqrt(128)

  float m_a = -1e30f, l_a = 0.f, m_b = -1e30f, l_b = 0.f;
  floatx4 oa[8] = {}, ob[8] = {};
  const int nt = 4 * qblk + 4;
  const int lastA = 4 * qblk + (w >> 2);   // last (mask) tile, group a
  const int lastB = lastA + 2;             // last (mask) tile, group b

  FSTAGE(0, 0);
  VMCNT0;
  GBAR;

  for (int t = 0; t < nt; t++) {
    const int cur = t & 1;
    if (t + 1 < nt) FSTAGE(t + 1, cur ^ 1);
    const char* Kl = fls + cur * 16384;
    const char* Vl = fls + 32768 + cur * 16384;
    // ---------------- group a ----------------
    if (t <= lastA) {
      floatx4 s4[4] = {};
      __builtin_amdgcn_s_setprio(1);
#pragma unroll
      for (int mf = 0; mf < 4; mf++) {
        const char* Krow = Kl + (mf * 16 + lr) * 256;
#pragma unroll
        for (int ks = 0; ks < 4; ks++) {
          short8 kf = *(const short8*)(Krow + (((ks * 4 + g) * 16) ^ swz));
          s4[mf] = __builtin_amdgcn_mfma_f32_16x16x32_bf16(kf, qfa[ks], s4[mf], 0, 0, 0);
        }
      }
      __builtin_amdgcn_s_setprio(0);
      float tm = -1e30f;
      if (t == lastA) {
#pragma unroll
        for (int mf = 0; mf < 4; mf++)
#pragma unroll
          for (int r = 0; r < 4; r++) {
            int kv = t * 64 + mf * 16 + g * 4 + r;
            float v = (kv > qra + lr) ? -1e30f : s4[mf][r] * scale;
            s4[mf][r] = v; tm = fmaxf(tm, v);
          }
      } else {
#pragma unroll
        for (int mf = 0; mf < 4; mf++)
#pragma unroll
          for (int r = 0; r < 4; r++) {
            float v = s4[mf][r] * scale;
            s4[mf][r] = v; tm = fmaxf(tm, v);
          }
      }
      tm = fmaxf(tm, __shfl_xor(tm, 16, 64));
      tm = fmaxf(tm, __shfl_xor(tm, 32, 64));
      float m_new = fmaxf(m_a, tm);
      float corr = __expf(m_a - m_new);
      float rs = 0.f;
#pragma unroll
      for (int mf = 0; mf < 4; mf++)
#pragma unroll
        for (int r = 0; r < 4; r++) {
          float p = __expf(s4[mf][r] - m_new);
          s4[mf][r] = p; rs += p;
        }
      rs += __shfl_xor(rs, 16, 64);
      rs += __shfl_xor(rs, 32, 64);
      l_a = l_a * corr + rs; m_a = m_new;
#pragma unroll
      for (int r = 0; r < 4; r++) {
        float cr = __shfl(corr, g * 4 + r, 64);
#pragma unroll
        for (int nf = 0; nf < 8; nf++) oa[nf][r] *= cr;
      }
#pragma unroll
      for (int mf = 0; mf < 4; mf++) {
        uint2 pv;
        pv.x = (uint32_t)f2bf(s4[mf][0]) | ((uint32_t)f2bf(s4[mf][1]) << 16);
        pv.y = (uint32_t)f2bf(s4[mf][2]) | ((uint32_t)f2bf(s4[mf][3]) << 16);
        *(uint2*)(Pw + lr * 128 + ((mf * 32 + g * 8) ^ (q7 << 4))) = pv;
      }
    }
    // ---------------- group b ----------------
    if (t <= lastB) {
      floatx4 s4[4] = {};
      __builtin_amdgcn_s_setprio(1);
#pragma unroll
      for (int mf = 0; mf < 4; mf++) {
        const char* Krow = Kl + (mf * 16 + lr) * 256;
#pragma unroll
        for (int ks = 0; ks < 4; ks++) {
          short8 kf = *(const short8*)(Krow + (((ks * 4 + g) * 16) ^ swz));
          s4[mf] = __builtin_amdgcn_mfma_f32_16x16x32_bf16(kf, qfb[ks], s4[mf], 0, 0, 0);
        }
      }
      __builtin_amdgcn_s_setprio(0);
      float tm = -1e30f;
      if (t == lastB) {
#pragma unroll
        for (int mf = 0; mf < 4; mf++)
#pragma unroll
          for (int r = 0; r < 4; r++) {
            int kv = t * 64 + mf * 16 + g * 4 + r;
            float v = (kv > qra + 128 + lr) ? -1e30f : s4[mf][r] * scale;
            s4[mf][r] = v; tm = fmaxf(tm, v);
          }
      } else {
#pragma unroll
        for (int mf = 0; mf < 4; mf++)
#pragma unroll
          for (int r = 0; r < 4; r++) {
            float v = s4[mf][r] * scale;
            s4[mf][r] = v; tm = fmaxf(tm, v);
          }
      }
      tm = fmaxf(tm, __shfl_xor(tm, 16, 64));
      tm = fmaxf(tm, __shfl_xor(tm, 32, 64));
      float m_new = fmaxf(m_b, tm);
      float corr = __expf(m_b - m_new);
      float rs = 0.f;
#pragma unroll
      for (int mf = 0; mf < 4; mf++)
#pragma unroll
        for (int r = 0; r < 4; r++) {
          float p = __expf(s4[mf][r] - m_new);
          s4[mf][r] = p; rs += p;
        }
      rs += __shfl_xor(rs, 16, 64);
      rs += __shfl_xor(rs, 32, 64);
      l_b = l_b * corr + rs; m_b = m_new;
#pragma unroll
      for (int r = 0; r < 4; r++) {
        float cr = __shfl(corr, g * 4 + r, 64);
#pragma unroll
        for (int nf = 0; nf < 8; nf++) ob[nf][r] *= cr;
      }
#pragma unroll
      for (int mf = 0; mf < 4; mf++) {
        uint2 pv;
        pv.x = (uint32_t)f2bf(s4[mf][0]) | ((uint32_t)f2bf(s4[mf][1]) << 16);
        pv.y = (uint32_t)f2bf(s4[mf][2]) | ((uint32_t)f2bf(s4[mf][3]) << 16);
        *(uint2*)(Pw + 2048 + lr * 128 + ((mf * 32 + g * 8) ^ (q7 << 4))) = pv;
      }
    }
    // ---------------- PV (V fragments shared by both groups) -------------
    __builtin_amdgcn_s_setprio(1);
#pragma unroll
    for (int ks2 = 0; ks2 < 2; ks2++) {
      short8 pa, pb;
      if (t <= lastA)
        pa = *(const short8*)(Pw + lr * 128 + ((ks2 * 64 + g * 16) ^ (q7 << 4)));
      if (t <= lastB)
        pb = *(const short8*)(Pw + 2048 + lr * 128 + ((ks2 * 64 + g * 16) ^ (q7 << 4)));
#pragma unroll
      for (int nf = 0; nf < 8; nf++) {
        short8 vf = *(const short8*)(Vl + (nf * 16 + lr) * 128 + (((ks2 * 4 + g) * 16) ^ swz));
        if (t <= lastA)
          oa[nf] = __builtin_amdgcn_mfma_f32_16x16x32_bf16(pa, vf, oa[nf], 0, 0, 0);
        if (t <= lastB)
          ob[nf] = __builtin_amdgcn_mfma_f32_16x16x32_bf16(pb, vf, ob[nf], 0, 0, 0);
      }
    }
    __builtin_amdgcn_s_setprio(0);
    VMCNT0;
    GBAR;
  }
  const float linva = 1.0f / l_a, linvb = 1.0f / l_b;
  ushort* outp = attn + ((size_t)(b * S_) + qra) * 4096 + h * 128;
#pragma unroll
  for (int r = 0; r < 4; r++) {
    float lia = __shfl(linva, g * 4 + r, 64);
    float lib = __shfl(linvb, g * 4 + r, 64);
    ushort* orow = outp + (size_t)(g * 4 + r) * 4096;
#pragma unroll
    for (int nf = 0; nf < 8; nf++) {
      orow[nf * 16 + lr] = f2bf(oa[nf][r] * lia);
      orow[(size_t)128 * 4096 + nf * 16 + lr] = f2bf(ob[nf][r] * lib);
    }
  }
}

extern "C" void kernel_launch(void* const* d_in, const int* in_sizes, int n_in,
                              void* d_out, int out_size, void* d_ws, size_t ws_size,
                              hipStream_t stream) {
  (void)in_sizes; (void)n_in; (void)out_size; (void)ws_size;
  const float* x    = (const float*)d_in[0];
  const float* wq   = (const float*)d_in[1];
  const float* wk   = (const float*)d_in[2];
  const float* wv   = (const float*)d_in[3];
  const float* wo   = (const float*)d_in[4];
  const float* lqa  = (const float*)d_in[5];
  const float* lqb  = (const float*)d_in[6];
  const float* lva  = (const float*)d_in[7];
  const float* lvb  = (const float*)d_in[8];
  const float* fcos = (const float*)d_in[9];
  const float* fsin = (const float*)d_in[10];

  char* ws = (char*)d_ws;
  ushort* xb   = (ushort*)(ws + 0);           // x bf16              [0,16) MB
  ushort* wT   = (ushort*)(ws + 16777216);    // [wq|wk|wv]^T bf16   [16,64) MB
  ushort* woT  = (ushort*)(ws + 67108864);    // wo^T bf16           [64,96) MB
  ushort* Qb   = (ushort*)(ws + 150994944);   // (b,h,s,d) bf16      [144,160) MB
  ushort* Kb   = (ushort*)(ws + 167772160);   // (b,kvh,s,d) bf16    [160,164) MB
  ushort* Vt   = (ushort*)(ws + 171966464);   // (b,kvh,d,s) bf16    [164,168) MB
  ushort* attn = (ushort*)(ws + 176160768);   // 2048x4096 bf16      [168,184) MB
  float*  xa   = (float*) (ws + 192937984);   // 2048x4 f32

  // 1) fused x convert + LoRA; weight transposes
  k_cvtlora<<<2048, 256, 0, stream>>>(x, lqa, lva, xb, xa);
  k_trw2<<<dim3(64, 64, 2), 256, 0, stream>>>(wq, wo, wT, woT, 4096, 4096);
  k_trw2<<<dim3(16, 64, 2), 256, 0, stream>>>(wk, wv, wT + (size_t)4096 * 4096,
                                              wT + (size_t)5120 * 4096, 1024, 4096);
  // 2) fused QKV GEMM + LoRA + RoPE -> Qb, Kb, transposed Vt
  k_gemmq<<<dim3(16, 16), 512, 0, stream>>>(xb, wT, Qb, Kb, Vt, xa, lqb, lvb,
                                            fcos, fsin);
  // 3) flash attention (256 q-rows/block) -> attn bf16
  k_flash<<<dim3(4, 32, 2), 512, 0, stream>>>(Qb, Kb, Vt, attn);
  // 4) output projection -> d_out f32 (grid 16x16 = 256 wg, full GPU)
  k_gemmo<<<dim3(16, 16), 512, 0, stream>>>(attn, woT, (float*)d_out);
}

// Round 13
// 291.098 us; speedup vs baseline: 1.0097x; 1.0097x over previous
//
#include <hip/hip_runtime.h>
#include <stdint.h>

#define B_ 2
#define S_ 1024
#define D_ 4096
#define H_ 32
#define KVH_ 8
#define HD_ 128

typedef short short8 __attribute__((ext_vector_type(8)));
typedef float floatx4 __attribute__((ext_vector_type(4)));

__device__ __forceinline__ ushort f2bf(float f) {
  union { float f; uint32_t u; } v; v.f = f;
  return (ushort)((v.u + 0x7FFFu + ((v.u >> 16) & 1u)) >> 16);
}
__device__ __forceinline__ float bf2f(ushort u) {
  union { uint32_t x; float f; } v; v.x = ((uint32_t)u) << 16; return v.f;
}

__device__ __forceinline__ void gload16(const void* g, void* l) {
  __builtin_amdgcn_global_load_lds((__attribute__((address_space(1))) void*)g,
                                   (__attribute__((address_space(3))) void*)l,
                                   16, 0, 0);
}

// ---- fused: x f32 -> bf16  AND  xa = x @ [lora_q_a | lora_v_a] ----
__global__ __launch_bounds__(256) void k_cvtlora(const float* __restrict__ x,
                                                 const float* __restrict__ qa,
                                                 const float* __restrict__ va,
                                                 ushort* __restrict__ xb,
                                                 float* __restrict__ xa) {
  const int row = blockIdx.x, t = threadIdx.x;
  const float* xr = x + (size_t)row * D_;
  ushort* xo = xb + (size_t)row * D_;
  float a0 = 0, a1 = 0, a2 = 0, a3 = 0;
#pragma unroll
  for (int it = 0; it < 4; it++) {
    const int i = it * 1024 + t * 4;
    float4 v = *(const float4*)(xr + i);
    ushort o4[4] = {f2bf(v.x), f2bf(v.y), f2bf(v.z), f2bf(v.w)};
    *(uint2*)(xo + i) = *(uint2*)o4;
    float4 q0 = *(const float4*)(qa + 2 * i);
    float4 q1 = *(const float4*)(qa + 2 * i + 4);
    float4 w0 = *(const float4*)(va + 2 * i);
    float4 w1 = *(const float4*)(va + 2 * i + 4);
    a0 += v.x * q0.x + v.y * q0.z + v.z * q1.x + v.w * q1.z;
    a1 += v.x * q0.y + v.y * q0.w + v.z * q1.y + v.w * q1.w;
    a2 += v.x * w0.x + v.y * w0.z + v.z * w1.x + v.w * w1.z;
    a3 += v.x * w0.y + v.y * w0.w + v.z * w1.y + v.w * w1.w;
  }
#pragma unroll
  for (int off = 32; off; off >>= 1) {
    a0 += __shfl_down(a0, off, 64);
    a1 += __shfl_down(a1, off, 64);
    a2 += __shfl_down(a2, off, 64);
    a3 += __shfl_down(a3, off, 64);
  }
  __shared__ float red[4][4];
  const int w = t >> 6, lane = t & 63;
  if (lane == 0) { red[w][0] = a0; red[w][1] = a1; red[w][2] = a2; red[w][3] = a3; }
  __syncthreads();
  if (t < 4)
    xa[(size_t)row * 4 + t] = red[0][t] + red[1][t] + red[2][t] + red[3][t];
}

// ---- f32 [R x C] -> bf16 transposed [C x R]; 64x64 tiles; z picks weight ----
__global__ __launch_bounds__(256) void k_trw4(const float* __restrict__ wq,
                                              const float* __restrict__ wo,
                                              const float* __restrict__ wk,
                                              const float* __restrict__ wv,
                                              ushort* __restrict__ oq,
                                              ushort* __restrict__ oo,
                                              ushort* __restrict__ ok,
                                              ushort* __restrict__ ov) {
  const int z = blockIdx.z;
  const bool narrow = (z >= 2);
  if (narrow && blockIdx.x >= 16) return;
  const float* in = (z == 0) ? wq : (z == 1) ? wo : (z == 2) ? wk : wv;
  ushort* out = (z == 0) ? oq : (z == 1) ? oo : (z == 2) ? ok : ov;
  const int in_stride = narrow ? 1024 : 4096;
  __shared__ float t[64][65];
  const int n0 = blockIdx.x * 64, k0 = blockIdx.y * 64;
  const int c4 = (threadIdx.x & 15) * 4, r = threadIdx.x >> 4;
#pragma unroll
  for (int rr = 0; rr < 64; rr += 16) {
    float4 v = *(const float4*)&in[(size_t)(k0 + r + rr) * in_stride + n0 + c4];
    t[r + rr][c4] = v.x; t[r + rr][c4 + 1] = v.y;
    t[r + rr][c4 + 2] = v.z; t[r + rr][c4 + 3] = v.w;
  }
  __syncthreads();
#pragma unroll
  for (int rr = 0; rr < 64; rr += 16) {
    const int n = r + rr;
    ushort o4[4] = {f2bf(t[c4][n]), f2bf(t[c4 + 1][n]),
                    f2bf(t[c4 + 2][n]), f2bf(t[c4 + 3][n])};
    *(uint2*)&out[(size_t)(n0 + n) * 4096 + k0 + c4] = *(uint2*)o4;
  }
}

#define GBAR __builtin_amdgcn_s_barrier()
#define VMCNT0 asm volatile("s_waitcnt vmcnt(0)" ::: "memory")
#define VMCNT6 asm volatile("s_waitcnt vmcnt(6)" ::: "memory")

// ==================== QKV GEMM: 128x384 tile, BK=64, 2-buffer =============
#define QSTG(T, SB) do {                                                     \
    const ushort* ga_ = A + (size_t)(m0 + w * 16 + qsr) * Kz + (T) * 64 + qsc; \
    char* la_ = qlds + (SB) * 65536 + w * 2048;                              \
    gload16(ga_, la_); gload16(ga_ + 8 * Kz, la_ + 1024);                    \
    _Pragma("unroll") for (int u_ = 0; u_ < 3; u_++) {                       \
      const ushort* gb_ = Bt + (size_t)(n0 + u_ * 128 + w * 16 + qsr) * Kz   \
                          + (T) * 64 + qsc;                                  \
      char* lb_ = qlds + (SB) * 65536 + 16384 + u_ * 16384 + w * 2048;       \
      gload16(gb_, lb_); gload16(gb_ + 8 * Kz, lb_ + 1024);                  \
    }                                                                        \
  } while (0)

__global__ __launch_bounds__(512, 2) void k_gemmq(const ushort* __restrict__ A,
                                                  const ushort* __restrict__ Bt,
                                                  ushort* __restrict__ Qb,
                                                  ushort* __restrict__ Kb,
                                                  ushort* __restrict__ Vt,
                                                  const float* __restrict__ xa,
                                                  const float* __restrict__ qb,
                                                  const float* __restrict__ vb,
                                                  const float* __restrict__ fcos,
                                                  const float* __restrict__ fsin) {
  __shared__ char qlds[131072];
  const int flat = blockIdx.y * 16 + blockIdx.x;
  const int swz_id = (flat & 7) * 32 + (flat >> 3);
  const int m0 = (swz_id >> 4) * 128, n0 = (swz_id & 15) * 384;
  const int tid = threadIdx.x, lane = tid & 63, w = tid >> 6;
  const int wr = w >> 2, wc = w & 3;
  const int lr = lane & 15, g = lane >> 4;
  const int swz = (lr & 7) * 16;
  const size_t Kz = 4096;
  const int qsr = lane >> 3;                       // 0..7
  const int qsc = ((lane & 7) ^ (qsr & 7)) * 8;    // pre-swizzled source col

  floatx4 acc[4][6] = {};
  short8 af[4][2], bfr[6][2];

  QSTG(0, 0);
  VMCNT0;
  GBAR;

  for (int t = 0; t < 64; ++t) {
    const int bu = t & 1;
    if (t + 1 < 64) QSTG(t + 1, bu ^ 1);
    const char* ab_ = qlds + bu * 65536 + (wr * 64 + lr) * 128;
#pragma unroll
    for (int fr = 0; fr < 4; fr++)
#pragma unroll
      for (int ks = 0; ks < 2; ks++)
        af[fr][ks] = *(const short8*)(ab_ + fr * 2048 + (((ks * 4 + g) * 16) ^ swz));
    const char* bb_ = qlds + bu * 65536 + 16384 + (wc * 32 + lr) * 128;
#pragma unroll
    for (int u = 0; u < 3; u++)
#pragma unroll
      for (int e = 0; e < 2; e++)
#pragma unroll
        for (int ks = 0; ks < 2; ks++)
          bfr[u * 2 + e][ks] = *(const short8*)(bb_ + u * 16384 + e * 2048 +
                                                (((ks * 4 + g) * 16) ^ swz));
    __builtin_amdgcn_s_setprio(1);
#pragma unroll
    for (int fr = 0; fr < 4; fr++)
#pragma unroll
      for (int u = 0; u < 6; u++)
#pragma unroll
        for (int ks = 0; ks < 2; ks++)
          acc[fr][u] = __builtin_amdgcn_mfma_f32_16x16x32_bf16(
              af[fr][ks], bfr[u][ks], acc[fr][u], 0, 0, 0);
    __builtin_amdgcn_s_setprio(0);
    VMCNT0;
    GBAR;
  }

  // epilogue: LoRA + RoPE fused; scatter to Qb/Kb/(transposed)Vt
#pragma unroll
  for (int fr = 0; fr < 4; fr++) {
    const int mb = m0 + wr * 64 + fr * 16 + g * 4;
    const int bb = mb >> 10, s0 = mb & 1023;
    float4 xa4[4];
#pragma unroll
    for (int r = 0; r < 4; r++) xa4[r] = *(const float4*)&xa[(size_t)(mb + r) * 4];
#pragma unroll
    for (int j = 0; j < 3; j++)
#pragma unroll
      for (int e = 0; e < 2; e++) {
        const int n = n0 + j * 128 + wc * 32 + e * 16 + lr;
        if (n < 5120) {
          const bool lq = (n < 4096);
          float b0 = 0.f, b1 = 0.f;
          if (lq) { b0 = qb[n]; b1 = qb[4096 + n]; }
          const int p = (n & 127) >> 1;
          const bool even = !(n & 1);
          const int d = n & 127;
          ushort* dst = lq ? (Qb + ((size_t)(bb * H_ + (n >> 7)) * S_) * HD_ + d)
                           : (Kb + ((size_t)(bb * KVH_ + ((n - 4096) >> 7)) * S_) * HD_ + d);
#pragma unroll
          for (int r = 0; r < 4; r++) {
            float cc = acc[fr][j * 2 + e][r];
            if (lq) cc += xa4[r].x * b0 + xa4[r].y * b1;
            float pv = __shfl_xor(cc, 1, 64);
            const int s = s0 + r;
            float c = fcos[s * 64 + p], sn = fsin[s * 64 + p];
            float o = even ? (cc * c - pv * sn) : (cc * c + pv * sn);
            dst[(size_t)s * HD_] = f2bf(o);
          }
        } else {
          const int vcol = n - 5120;
          const float b0 = vb[vcol], b1 = vb[1024 + vcol];
          ushort v4[4];
#pragma unroll
          for (int r = 0; r < 4; r++)
            v4[r] = f2bf(acc[fr][j * 2 + e][r] + xa4[r].z * b0 + xa4[r].w * b1);
          *(uint2*)&Vt[(size_t)((bb * 8 + (vcol >> 7)) * 128 + (vcol & 127)) * 1024 + s0] =
              *(uint2*)v4;
        }
      }
  }
}

// ==================== out-proj GEMM: 128x256 tile, BK=64, 3-buffer ========
#define OSTG(T, SB) do {                                                     \
    const ushort* ga_ = A + (size_t)(m0 + w * 16 + osr) * Kz + (T) * 64 + osc; \
    char* la_ = olds + (SB) * 49152 + w * 2048;                              \
    gload16(ga_, la_); gload16(ga_ + 8 * Kz, la_ + 1024);                    \
    _Pragma("unroll") for (int u_ = 0; u_ < 2; u_++) {                       \
      const ushort* gb_ = Bt + (size_t)(n0 + u_ * 128 + w * 16 + osr) * Kz + (T) * 64 + osc; \
      char* lb_ = olds + (SB) * 49152 + 16384 + u_ * 16384 + w * 2048;       \
      gload16(gb_, lb_); gload16(gb_ + 8 * Kz, lb_ + 1024);                  \
    }                                                                        \
  } while (0)

#define OTILE(T, RB) do {                                                    \
    if ((T) + 2 < 64) OSTG((T) + 2, ((RB) + 2) % 3);                         \
    const char* ab_ = olds + (RB) * 49152 + (wr * 64 + lr) * 128;            \
    _Pragma("unroll") for (int fr = 0; fr < 4; fr++)                         \
    _Pragma("unroll") for (int ks = 0; ks < 2; ks++)                         \
      af[fr][ks] = *(const short8*)(ab_ + fr * 2048 + (((ks * 4 + g) * 16) ^ swz)); \
    const char* bb_ = olds + (RB) * 49152 + 16384 + (wc * 32 + lr) * 128;    \
    _Pragma("unroll") for (int u_ = 0; u_ < 2; u_++)                         \
    _Pragma("unroll") for (int e_ = 0; e_ < 2; e_++)                         \
    _Pragma("unroll") for (int ks = 0; ks < 2; ks++)                         \
      bfr[u_ * 2 + e_][ks] = *(const short8*)(bb_ + u_ * 16384 + e_ * 2048 + (((ks * 4 + g) * 16) ^ swz)); \
    __builtin_amdgcn_s_setprio(1);                                           \
    _Pragma("unroll") for (int fr = 0; fr < 4; fr++)                         \
    _Pragma("unroll") for (int u_ = 0; u_ < 4; u_++)                         \
    _Pragma("unroll") for (int ks = 0; ks < 2; ks++)                         \
      acc[fr][u_] = __builtin_amdgcn_mfma_f32_16x16x32_bf16(                 \
          af[fr][ks], bfr[u_][ks], acc[fr][u_], 0, 0, 0);                    \
    __builtin_amdgcn_s_setprio(0);                                           \
    if ((T) + 2 < 64) { VMCNT6; } else { VMCNT0; }                           \
    GBAR;                                                                    \
  } while (0)

__global__ __launch_bounds__(512, 2) void k_gemmo(const ushort* __restrict__ A,
                                                  const ushort* __restrict__ Bt,
                                                  float* __restrict__ C) {
  __shared__ char olds[147456];
  const int flat = blockIdx.y * 16 + blockIdx.x;
  const int swz_id = (flat & 7) * 32 + (flat >> 3);
  const int m0 = (swz_id >> 4) * 128, n0 = (swz_id & 15) * 256;
  const int tid = threadIdx.x, lane = tid & 63, w = tid >> 6;
  const int wr = w >> 2, wc = w & 3;
  const int lr = lane & 15, g = lane >> 4;
  const int swz = (lr & 7) * 16;
  const size_t Kz = 4096;
  const int osr = lane >> 3;
  const int osc = ((lane & 7) ^ (osr & 7)) * 8;

  floatx4 acc[4][4] = {};
  short8 af[4][2], bfr[4][2];

  OSTG(0, 0); OSTG(1, 1);
  VMCNT6;
  GBAR;

  for (int tt = 0; tt < 63; tt += 3) {
    OTILE(tt + 0, 0);
    OTILE(tt + 1, 1);
    OTILE(tt + 2, 2);
  }
  OTILE(63, 0);

#pragma unroll
  for (int fr = 0; fr < 4; fr++) {
    const int mb = m0 + wr * 64 + fr * 16 + g * 4;
#pragma unroll
    for (int j = 0; j < 2; j++)
#pragma unroll
      for (int e = 0; e < 2; e++) {
        const int n = n0 + j * 128 + wc * 32 + e * 16 + lr;
#pragma unroll
        for (int r = 0; r < 4; r++)
          C[(size_t)(mb + r) * 4096 + n] = acc[fr][j * 2 + e][r];
      }
  }
}

// ==================== flash attention, 128 q-rows/block (r11 best) ========
#define FSTAGE(T, DB) do {                                                   \
    _Pragma("unroll") for (int i_ = 0; i_ < 4; i_++) {                       \
      gload16(Kg + (size_t)((T) * 64 + i_ * 16 + k_srow) * HD_ + k_scol,     \
              fls + (DB) * 16384 + i_ * 4096 + w * 1024);                    \
      gload16(Vg + (size_t)(i_ * 32 + v_srow) * S_ + (T) * 64 + v_scol,      \
              fls + 32768 + (DB) * 16384 + i_ * 4096 + w * 1024);            \
    }                                                                        \
  } while (0)

__global__ __launch_bounds__(256, 2) void k_flash(const ushort* __restrict__ Qb,
                                                  const ushort* __restrict__ Kb,
                                                  const ushort* __restrict__ Vt,
                                                  ushort* __restrict__ attn) {
  __shared__ char fls[81920];  // K dbuf 32KB | V dbuf 32KB | P 16KB
  const int qblk = (gridDim.x - 1) - blockIdx.x;  // 0..7, heavy first
  const int h = blockIdx.y, b = blockIdx.z;
  const int kvh = h >> 2;
  const int tid = threadIdx.x, w = tid >> 6, lane = tid & 63;
  const int lr = lane & 15, g = lane >> 4;
  const int swz = (lr & 7) * 16;
  const int qra = qblk * 128 + w * 16;     // group a rows; group b = +64
  const ushort* Qrow = Qb + ((size_t)(b * H_ + h) * S_ + qra + lr) * HD_;
  short8 qfa[4], qfb[4];
#pragma unroll
  for (int ks = 0; ks < 4; ks++) {
    qfa[ks] = *(const short8*)(Qrow + ks * 32 + g * 8);
    qfb[ks] = *(const short8*)(Qrow + 64 * HD_ + ks * 32 + g * 8);
  }
  const ushort* Kg = Kb + (size_t)(b * KVH_ + kvh) * S_ * HD_;
  const ushort* Vg = Vt + (size_t)(b * KVH_ + kvh) * HD_ * S_;
  char* Pw = fls + 65536 + w * 4096;       // a at +0, b at +2048
  const int q7 = lr & 7;
  const int k_srow = tid >> 4;
  const int k_scol = ((tid & 15) ^ (k_srow & 7)) * 8;
  const int v_srow = tid >> 3;
  const int v_scol = ((tid & 7) ^ (v_srow & 7)) * 8;
  const float scale = 0.088388347648318447f;  // 1/sqrt(128)

  float m_a = -1e30f, l_a = 0.f, m_b = -1e30f, l_b = 0.f;
  floatx4 oa[8] = {}, ob[8] = {};
  const int nt = 2 * qblk + 2;
  const int lastA = 2 * qblk;  // last (and mask) tile for group a

  FSTAGE(0, 0);
  VMCNT0;
  GBAR;

  for (int t = 0; t < nt; t++) {
    const int cur = t & 1;
    if (t + 1 < nt) FSTAGE(t + 1, cur ^ 1);
    const char* Kl = fls + cur * 16384;
    const char* Vl = fls + 32768 + cur * 16384;
    // ---------------- group a ----------------
    if (t <= lastA) {
      floatx4 s4[4] = {};
      __builtin_amdgcn_s_setprio(1);
#pragma unroll
      for (int mf = 0; mf < 4; mf++) {
        const char* Krow = Kl + (mf * 16 + lr) * 256;
#pragma unroll
        for (int ks = 0; ks < 4; ks++) {
          short8 kf = *(const short8*)(Krow + (((ks * 4 + g) * 16) ^ swz));
          s4[mf] = __builtin_amdgcn_mfma_f32_16x16x32_bf16(kf, qfa[ks], s4[mf], 0, 0, 0);
        }
      }
      __builtin_amdgcn_s_setprio(0);
      float tm = -1e30f;
      if (t == lastA) {
#pragma unroll
        for (int mf = 0; mf < 4; mf++)
#pragma unroll
          for (int r = 0; r < 4; r++) {
            int kv = t * 64 + mf * 16 + g * 4 + r;
            float v = (kv > qra + lr) ? -1e30f : s4[mf][r] * scale;
            s4[mf][r] = v; tm = fmaxf(tm, v);
          }
      } else {
#pragma unroll
        for (int mf = 0; mf < 4; mf++)
#pragma unroll
          for (int r = 0; r < 4; r++) {
            float v = s4[mf][r] * scale;
            s4[mf][r] = v; tm = fmaxf(tm, v);
          }
      }
      tm = fmaxf(tm, __shfl_xor(tm, 16, 64));
      tm = fmaxf(tm, __shfl_xor(tm, 32, 64));
      float m_new = fmaxf(m_a, tm);
      float corr = __expf(m_a - m_new);
      float rs = 0.f;
#pragma unroll
      for (int mf = 0; mf < 4; mf++)
#pragma unroll
        for (int r = 0; r < 4; r++) {
          float p = __expf(s4[mf][r] - m_new);
          s4[mf][r] = p; rs += p;
        }
      rs += __shfl_xor(rs, 16, 64);
      rs += __shfl_xor(rs, 32, 64);
      l_a = l_a * corr + rs; m_a = m_new;
#pragma unroll
      for (int r = 0; r < 4; r++) {
        float cr = __shfl(corr, g * 4 + r, 64);
#pragma unroll
        for (int nf = 0; nf < 8; nf++) oa[nf][r] *= cr;
      }
#pragma unroll
      for (int mf = 0; mf < 4; mf++) {
        uint2 pv;
        pv.x = (uint32_t)f2bf(s4[mf][0]) | ((uint32_t)f2bf(s4[mf][1]) << 16);
        pv.y = (uint32_t)f2bf(s4[mf][2]) | ((uint32_t)f2bf(s4[mf][3]) << 16);
        *(uint2*)(Pw + lr * 128 + ((mf * 32 + g * 8) ^ (q7 << 4))) = pv;
      }
    }
    // ---------------- group b ----------------
    {
      floatx4 s4[4] = {};
      __builtin_amdgcn_s_setprio(1);
#pragma unroll
      for (int mf = 0; mf < 4; mf++) {
        const char* Krow = Kl + (mf * 16 + lr) * 256;
#pragma unroll
        for (int ks = 0; ks < 4; ks++) {
          short8 kf = *(const short8*)(Krow + (((ks * 4 + g) * 16) ^ swz));
          s4[mf] = __builtin_amdgcn_mfma_f32_16x16x32_bf16(kf, qfb[ks], s4[mf], 0, 0, 0);
        }
      }
      __builtin_amdgcn_s_setprio(0);
      float tm = -1e30f;
      if (t == nt - 1) {
#pragma unroll
        for (int mf = 0; mf < 4; mf++)
#pragma unroll
          for (int r = 0; r < 4; r++) {
            int kv = t * 64 + mf * 16 + g * 4 + r;
            float v = (kv > qra + 64 + lr) ? -1e30f : s4[mf][r] * scale;
            s4[mf][r] = v; tm = fmaxf(tm, v);
          }
      } else {
#pragma unroll
        for (int mf = 0; mf < 4; mf++)
#pragma unroll
          for (int r = 0; r < 4; r++) {
            float v = s4[mf][r] * scale;
            s4[mf][r] = v; tm = fmaxf(tm, v);
          }
      }
      tm = fmaxf(tm, __shfl_xor(tm, 16, 64));
      tm = fmaxf(tm, __shfl_xor(tm, 32, 64));
      float m_new = fmaxf(m_b, tm);
      float corr = __expf(m_b - m_new);
      float rs = 0.f;
#pragma unroll
      for (int mf = 0; mf < 4; mf++)
#pragma unroll
        for (int r = 0; r < 4; r++) {
          float p = __expf(s4[mf][r] - m_new);
          s4[mf][r] = p; rs += p;
        }
      rs += __shfl_xor(rs, 16, 64);
      rs += __shfl_xor(rs, 32, 64);
      l_b = l_b * corr + rs; m_b = m_new;
#pragma unroll
      for (int r = 0; r < 4; r++) {
        float cr = __shfl(corr, g * 4 + r, 64);
#pragma unroll
        for (int nf = 0; nf < 8; nf++) ob[nf][r] *= cr;
      }
#pragma unroll
      for (int mf = 0; mf < 4; mf++) {
        uint2 pv;
        pv.x = (uint32_t)f2bf(s4[mf][0]) | ((uint32_t)f2bf(s4[mf][1]) << 16);
        pv.y = (uint32_t)f2bf(s4[mf][2]) | ((uint32_t)f2bf(s4[mf][3]) << 16);
        *(uint2*)(Pw + 2048 + lr * 128 + ((mf * 32 + g * 8) ^ (q7 << 4))) = pv;
      }
    }
    // ---------------- PV (V fragments shared by both groups) -------------
    __builtin_amdgcn_s_setprio(1);
#pragma unroll
    for (int ks2 = 0; ks2 < 2; ks2++) {
      short8 pb = *(const short8*)(Pw + 2048 + lr * 128 + ((ks2 * 64 + g * 16) ^ (q7 << 4)));
      short8 pa = pb;
      if (t <= lastA)
        pa = *(const short8*)(Pw + lr * 128 + ((ks2 * 64 + g * 16) ^ (q7 << 4)));
#pragma unroll
      for (int nf = 0; nf < 8; nf++) {
        short8 vf = *(const short8*)(Vl + (nf * 16 + lr) * 128 + (((ks2 * 4 + g) * 16) ^ swz));
        if (t <= lastA)
          oa[nf] = __builtin_amdgcn_mfma_f32_16x16x32_bf16(pa, vf, oa[nf], 0, 0, 0);
        ob[nf] = __builtin_amdgcn_mfma_f32_16x16x32_bf16(pb, vf, ob[nf], 0, 0, 0);
      }
    }
    __builtin_amdgcn_s_setprio(0);
    VMCNT0;
    GBAR;
  }
  const float linva = 1.0f / l_a, linvb = 1.0f / l_b;
  ushort* outp = attn + ((size_t)(b * S_) + qra) * 4096 + h * 128;
#pragma unroll
  for (int r = 0; r < 4; r++) {
    float lia = __shfl(linva, g * 4 + r, 64);
    float lib = __shfl(linvb, g * 4 + r, 64);
    ushort* orow = outp + (size_t)(g * 4 + r) * 4096;
#pragma unroll
    for (int nf = 0; nf < 8; nf++) {
      orow[nf * 16 + lr] = f2bf(oa[nf][r] * lia);
      orow[(size_t)64 * 4096 + nf * 16 + lr] = f2bf(ob[nf][r] * lib);
    }
  }
}

extern "C" void kernel_launch(void* const* d_in, const int* in_sizes, int n_in,
                              void* d_out, int out_size, void* d_ws, size_t ws_size,
                              hipStream_t stream) {
  (void)in_sizes; (void)n_in; (void)out_size; (void)ws_size;
  const float* x    = (const float*)d_in[0];
  const float* wq   = (const float*)d_in[1];
  const float* wk   = (const float*)d_in[2];
  const float* wv   = (const float*)d_in[3];
  const float* wo   = (const float*)d_in[4];
  const float* lqa  = (const float*)d_in[5];
  const float* lqb  = (const float*)d_in[6];
  const float* lva  = (const float*)d_in[7];
  const float* lvb  = (const float*)d_in[8];
  const float* fcos = (const float*)d_in[9];
  const float* fsin = (const float*)d_in[10];

  char* ws = (char*)d_ws;
  ushort* xb   = (ushort*)(ws + 0);           // x bf16              [0,16) MB
  ushort* wT   = (ushort*)(ws + 16777216);    // [wq|wk|wv]^T bf16   [16,64) MB
  ushort* woT  = (ushort*)(ws + 67108864);    // wo^T bf16           [64,96) MB
  ushort* Qb   = (ushort*)(ws + 150994944);   // (b,h,s,d) bf16      [144,160) MB
  ushort* Kb   = (ushort*)(ws + 167772160);   // (b,kvh,s,d) bf16    [160,164) MB
  ushort* Vt   = (ushort*)(ws + 171966464);   // (b,kvh,d,s) bf16    [164,168) MB
  ushort* attn = (ushort*)(ws + 176160768);   // 2048x4096 bf16      [168,184) MB
  float*  xa   = (float*) (ws + 192937984);   // 2048x4 f32

  // 1) fused x convert + LoRA; all 4 weight transposes in one launch
  k_cvtlora<<<2048, 256, 0, stream>>>(x, lqa, lva, xb, xa);
  k_trw4<<<dim3(64, 64, 4), 256, 0, stream>>>(
      wq, wo, wk, wv, wT, woT,
      wT + (size_t)4096 * 4096, wT + (size_t)5120 * 4096);
  // 2) fused QKV GEMM + LoRA + RoPE -> Qb, Kb, transposed Vt
  k_gemmq<<<dim3(16, 16), 512, 0, stream>>>(xb, wT, Qb, Kb, Vt, xa, lqb, lvb,
                                            fcos, fsin);
  // 3) flash attention (128 q-rows/block) -> attn bf16
  k_flash<<<dim3(8, 32, 2), 256, 0, stream>>>(Qb, Kb, Vt, attn);
  // 4) output projection -> d_out f32 (grid 16x16 = 256 wg, full GPU)
  k_gemmo<<<dim3(16, 16), 512, 0, stream>>>(attn, woT, (float*)d_out);
}